// Round 5
// baseline (3597.697 us; speedup 1.0000x reference)
//
#include <hip/hip_runtime.h>
#include <hip/hip_bf16.h>
#include <hip/hip_fp16.h>

// ---------------------------------------------------------------------------
// 3-layer GRU (Keras v2, reset_after=True), B=64 T=2048 F=H=128, OUT=5.
// Round 5:
//   gru_rec v5: G=2 restructure — thread owns a unit PAIR (u0,u1), kh in 0..3.
//     256 thr (4 waves, 1/SIMD). Halves LDS broadcast instrs (32->16 b128 per
//     step per CU) and dot2 issue (192cy/SIMD). DPP quad reduce, soft barrier,
//     ring-4 xw prefetch kept from v4.
//   in_proj v5: gru-style. Weights resident in VGPRs (96/thread), x staged in
//     LDS 64 rows/stage, WG sweeps 512 rows -> weight L2 traffic amortized
//     512x (was 12.9GB/layer -> ~0.1GB). pack_w dropped.
// xw row layout: [zr interleaved f16 x256 | h f16 x128]; z,r rec-bias folded.
// ws: xw f16 100.6MB + h f16 33.5MB.
// ---------------------------------------------------------------------------

#define HID   128
#define H3    384
#define OUTD  5
#define T_SEQ 2048

typedef _Float16 f16x2 __attribute__((ext_vector_type(2)));
typedef _Float16 f16x4 __attribute__((ext_vector_type(4)));
typedef _Float16 f16x8 __attribute__((ext_vector_type(8)));

__device__ __forceinline__ float fdot2(f16x2 a, f16x2 b, float c) {
#if __has_builtin(__builtin_amdgcn_fdot2)
    return __builtin_amdgcn_fdot2(a, b, c, false);   // v_dot2_f32_f16
#else
    return fmaf((float)a.x, (float)b.x, fmaf((float)a.y, (float)b.y, c));
#endif
}

__device__ __forceinline__ float fexp2(float x) {
#if __has_builtin(__builtin_amdgcn_exp2f)
    return __builtin_amdgcn_exp2f(x);
#else
    return exp2f(x);
#endif
}

__device__ __forceinline__ float frcp(float x) {
#if __has_builtin(__builtin_amdgcn_rcpf)
    return __builtin_amdgcn_rcpf(x);
#else
    return 1.f / x;
#endif
}

// sigmoid(x) = 1/(1+exp(-x)); saturates correctly at +-inf, no clamp needed.
__device__ __forceinline__ float fsigmoid(float x) {
    return frcp(1.f + fexp2(x * -1.4426950408889634f));
}

// tanh(x) = 1 - 2/(1+exp(2x)); saturates correctly at +-inf.
__device__ __forceinline__ float ftanh_(float x) {
    return fmaf(-2.f, frcp(1.f + fexp2(x * 2.8853900817779268f)), 1.f);
}

// barrier that does NOT drain vmcnt (unlike __syncthreads). LDS handoff only
// needs lgkmcnt(0); global prefetch loads stay in flight across steps.
__device__ __forceinline__ void soft_barrier() {
    asm volatile("s_waitcnt lgkmcnt(0)\n\ts_barrier" ::: "memory");
}

// butterfly sum over the kh quad (lanes xor 1, xor 2) on the VALU pipe
__device__ __forceinline__ float quad_sum(float x) {
#if __has_builtin(__builtin_amdgcn_mov_dpp)
    int i1 = __builtin_amdgcn_mov_dpp(__float_as_int(x), 0xB1, 0xF, 0xF, true); // [1,0,3,2]
    x += __int_as_float(i1);
    int i2 = __builtin_amdgcn_mov_dpp(__float_as_int(x), 0x4E, 0xF, 0xF, true); // [2,3,0,1]
    x += __int_as_float(i2);
#else
    x += __shfl_xor(x, 1);
    x += __shfl_xor(x, 2);
#endif
    return x;
}

// ---------------------------------------------------------------------------
// in_proj v5: XW[r,:] = x[r,:] @ Kw + biases. gru-style: thread (j2,kh) owns
// units u0=2*j2, u1=u0+1 for k-quarter kh; weights resident as f16x2 in VGPRs;
// x staged in LDS 64 rows per stage; each WG sweeps rows_per_wg rows.
// Output layout per row: [z0 r0 z1 r1 ... (256)] then [h x128].
// z,r get b_in + b_rec folded; h gets b_in only.
// NOTE: assumes R % (grid*64) == 0 (exact for B*T=131072, grid=256).
// ---------------------------------------------------------------------------
#define XS_STRIDE 136   // f16 elems per staged row: 272B = 17*16B (bank spread)

template<bool F32IN>
__global__ __launch_bounds__(256, 1) void in_proj(
    const void* __restrict__ Xv,     // [R,128] fp32 or f16
    const float* __restrict__ Kw,    // [128,384]
    const float* __restrict__ bias,  // [2,384]: row0 input, row1 recurrent
    _Float16*   __restrict__ XW,     // [R,384] layout zr|h
    int rows_per_wg)
{
    const int t  = threadIdx.x;
    const int j2 = t >> 2;       // unit pair 0..63
    const int kh = t & 3;        // k-quarter
    const int k0 = kh * 32;
    const int u0 = 2 * j2, u1 = u0 + 1;

    __shared__ __align__(16) _Float16 xs[64 * XS_STRIDE];

    // resident weights: 2 units x 3 gates x 16 f16x2 = 96 VGPRs
    f16x2 wz0[16], wr0[16], wh0[16], wz1[16], wr1[16], wh1[16];
#pragma unroll
    for (int p = 0; p < 16; ++p) {
        const int k = k0 + 2 * p;
        const float* r0p = Kw + (size_t)k * H3;
        const float* r1p = Kw + (size_t)(k + 1) * H3;
        f16x2 a;
        a.x = (_Float16)r0p[u0];       a.y = (_Float16)r1p[u0];       wz0[p] = a;
        a.x = (_Float16)r0p[u0 + 128]; a.y = (_Float16)r1p[u0 + 128]; wr0[p] = a;
        a.x = (_Float16)r0p[u0 + 256]; a.y = (_Float16)r1p[u0 + 256]; wh0[p] = a;
        a.x = (_Float16)r0p[u1];       a.y = (_Float16)r1p[u1];       wz1[p] = a;
        a.x = (_Float16)r0p[u1 + 128]; a.y = (_Float16)r1p[u1 + 128]; wr1[p] = a;
        a.x = (_Float16)r0p[u1 + 256]; a.y = (_Float16)r1p[u1 + 256]; wh1[p] = a;
    }
    const float bz0 = bias[u0]       + bias[384 + u0];
    const float br0 = bias[128 + u0] + bias[384 + 128 + u0];
    const float bh0 = bias[256 + u0];
    const float bz1 = bias[u1]       + bias[384 + u1];
    const float br1 = bias[128 + u1] + bias[384 + 128 + u1];
    const float bh1 = bias[256 + u1];

    const int row0 = blockIdx.x * rows_per_wg;
    const int lr   = t >> 2;     // stage-load row for this thread (64 rows, 4 thr/row)

    for (int stage = 0; stage < rows_per_wg; stage += 64) {
        // ---- stage 64 rows of x into LDS (f16) ----
        {
            const int gr = row0 + stage + lr;
            f16x8* dst = (f16x8*)(&xs[lr * XS_STRIDE + k0]);
            if (F32IN) {
                const float4* src = (const float4*)((const float*)Xv + (size_t)gr * HID + k0);
#pragma unroll
                for (int i = 0; i < 4; ++i) {
                    const float4 a = src[2 * i], b4 = src[2 * i + 1];
                    f16x8 v;
                    v[0] = (_Float16)a.x;  v[1] = (_Float16)a.y;
                    v[2] = (_Float16)a.z;  v[3] = (_Float16)a.w;
                    v[4] = (_Float16)b4.x; v[5] = (_Float16)b4.y;
                    v[6] = (_Float16)b4.z; v[7] = (_Float16)b4.w;
                    dst[i] = v;
                }
            } else {
                const f16x8* src = (const f16x8*)((const _Float16*)Xv + (size_t)gr * HID + k0);
#pragma unroll
                for (int i = 0; i < 4; ++i) dst[i] = src[i];
            }
        }
        __syncthreads();

        // ---- compute 64 rows ----
#pragma unroll 2
        for (int r = 0; r < 64; ++r) {
            const f16x8* hp = (const f16x8*)(&xs[r * XS_STRIDE + k0]);
            float az0 = 0.f, ar0 = 0.f, ah0 = 0.f, az1 = 0.f, ar1 = 0.f, ah1 = 0.f;
#pragma unroll
            for (int i = 0; i < 4; ++i) {
                union { f16x8 v; f16x2 p[4]; } u;
                u.v = hp[i];
#pragma unroll
                for (int q = 0; q < 4; ++q) {
                    const f16x2 hv = u.p[q];
                    az0 = fdot2(hv, wz0[4 * i + q], az0);
                    ar0 = fdot2(hv, wr0[4 * i + q], ar0);
                    ah0 = fdot2(hv, wh0[4 * i + q], ah0);
                    az1 = fdot2(hv, wz1[4 * i + q], az1);
                    ar1 = fdot2(hv, wr1[4 * i + q], ar1);
                    ah1 = fdot2(hv, wh1[4 * i + q], ah1);
                }
            }
            az0 = quad_sum(az0); ar0 = quad_sum(ar0); ah0 = quad_sum(ah0);
            az1 = quad_sum(az1); ar1 = quad_sum(ar1); ah1 = quad_sum(ah1);

            if (kh == 0) {
                _Float16* orow = XW + (size_t)(row0 + stage + r) * H3;
                f16x4 zr;
                zr[0] = (_Float16)(az0 + bz0);
                zr[1] = (_Float16)(ar0 + br0);
                zr[2] = (_Float16)(az1 + bz1);
                zr[3] = (_Float16)(ar1 + br1);
                *(f16x4*)(orow + 4 * j2) = zr;
                f16x2 hh;
                hh.x = (_Float16)(ah0 + bh0);
                hh.y = (_Float16)(ah1 + bh1);
                *(f16x2*)(orow + 256 + 2 * j2) = hh;
            }
        }
        __syncthreads();
    }
}

// ---------------------------------------------------------------------------
// gru_rec v5: one WG (256 thr, 4 waves) per batch. thread (j2,kh) owns units
// u0=2*j2,u1 for k-quarter kh. 16 b128 LDS broadcasts/step (was 32); DPP quad
// reduce; h f16 double-buffer in LDS; ring-4 xw prefetch; soft barrier.
// ---------------------------------------------------------------------------
__global__ __launch_bounds__(256, 1) void gru_rec(
    const _Float16* __restrict__ xw,   // [B*T, 384]  layout zr|h
    const float*    __restrict__ rk,   // [128, 384]
    const float*    __restrict__ bias, // [2, 384], row 1 = recurrent bias
    _Float16*       __restrict__ h_out,// [B*T, 128] f16
    int T)
{
    const int b  = blockIdx.x;
    const int t  = threadIdx.x;
    const int j2 = t >> 2;      // unit pair 0..63
    const int kh = t & 3;       // k-quarter
    const int k0 = kh * 32;
    const int u0 = 2 * j2, u1 = u0 + 1;

    __shared__ __align__(16) _Float16 hbuf[2][HID];

    // resident weights: 2 units x 3 gates x 16 f16x2 = 96 VGPRs
    f16x2 wz0[16], wr0[16], wh0[16], wz1[16], wr1[16], wh1[16];
#pragma unroll
    for (int p = 0; p < 16; ++p) {
        const int k = k0 + 2 * p;
        const float* r0p = rk + (size_t)k * H3;
        const float* r1p = rk + (size_t)(k + 1) * H3;
        f16x2 a;
        a.x = (_Float16)r0p[u0];       a.y = (_Float16)r1p[u0];       wz0[p] = a;
        a.x = (_Float16)r0p[u0 + 128]; a.y = (_Float16)r1p[u0 + 128]; wr0[p] = a;
        a.x = (_Float16)r0p[u0 + 256]; a.y = (_Float16)r1p[u0 + 256]; wh0[p] = a;
        a.x = (_Float16)r0p[u1];       a.y = (_Float16)r1p[u1];       wz1[p] = a;
        a.x = (_Float16)r0p[u1 + 128]; a.y = (_Float16)r1p[u1 + 128]; wr1[p] = a;
        a.x = (_Float16)r0p[u1 + 256]; a.y = (_Float16)r1p[u1 + 256]; wh1[p] = a;
    }
    const float bh0 = bias[384 + 256 + u0];   // only h-gate recurrent bias survives
    const float bh1 = bias[384 + 256 + u1];

    if (t < HID) { hbuf[0][t] = (_Float16)0.f; hbuf[1][t] = (_Float16)0.f; }

    const _Float16* xwb = xw + (size_t)b * T * H3;
    _Float16*       hob = h_out + (size_t)b * T * HID;

    // prefetch ring depth 4: per slot (z0,r0,z1,r1) f16x4 + (h0,h1) f16x2
    f16x4 zrA, zrB, zrC, zrD;
    f16x2 hhA, hhB, hhC, hhD;
    {
        const _Float16* p0 = xwb;
        zrA = *(const f16x4*)(p0 + 4 * j2); hhA = *(const f16x2*)(p0 + 256 + 2 * j2);
        const _Float16* p1 = xwb + H3;
        zrB = *(const f16x4*)(p1 + 4 * j2); hhB = *(const f16x2*)(p1 + 256 + 2 * j2);
        const _Float16* p2 = xwb + 2 * H3;
        zrC = *(const f16x4*)(p2 + 4 * j2); hhC = *(const f16x2*)(p2 + 256 + 2 * j2);
        const _Float16* p3 = xwb + 3 * H3;
        zrD = *(const f16x4*)(p3 + 4 * j2); hhD = *(const f16x2*)(p3 + 256 + 2 * j2);
    }

    float h0_old = 0.f, h1_old = 0.f;
    __syncthreads();

    auto STEP = [&](int step, int rbuf, f16x4& qzr, f16x2& qh) {
        const f16x8* hp = (const f16x8*)(&hbuf[rbuf][k0]);
        float sz0 = 0.f, sr0 = 0.f, sh0 = 0.f, sz1 = 0.f, sr1 = 0.f, sh1 = 0.f;
#pragma unroll
        for (int i = 0; i < 4; ++i) {
            union { f16x8 v; f16x2 p[4]; } u;
            u.v = hp[i];
#pragma unroll
            for (int q = 0; q < 4; ++q) {
                const f16x2 hv = u.p[q];
                sz0 = fdot2(hv, wz0[4 * i + q], sz0);
                sr0 = fdot2(hv, wr0[4 * i + q], sr0);
                sh0 = fdot2(hv, wh0[4 * i + q], sh0);
                sz1 = fdot2(hv, wz1[4 * i + q], sz1);
                sr1 = fdot2(hv, wr1[4 * i + q], sr1);
                sh1 = fdot2(hv, wh1[4 * i + q], sh1);
            }
        }
        sz0 = quad_sum(sz0); sr0 = quad_sum(sr0); sh0 = quad_sum(sh0);
        sz1 = quad_sum(sz1); sr1 = quad_sum(sr1); sh1 = quad_sum(sh1);

        const float xz0 = (float)qzr[0], xr0 = (float)qzr[1];
        const float xz1 = (float)qzr[2], xr1 = (float)qzr[3];
        const float xh0 = (float)qh.x,   xh1 = (float)qh.y;
        if (step + 4 < T) {                       // reload this slot for step+4
            const _Float16* p = xwb + (size_t)(step + 4) * H3;
            qzr = *(const f16x4*)(p + 4 * j2);
            qh  = *(const f16x2*)(p + 256 + 2 * j2);
        }

        const float z0  = fsigmoid(xz0 + sz0);
        const float r0  = fsigmoid(xr0 + sr0);
        const float hh0 = ftanh_(xh0 + (sh0 + bh0) * r0);
        const float hn0 = fmaf(z0, h0_old - hh0, hh0);
        const float z1  = fsigmoid(xz1 + sz1);
        const float r1  = fsigmoid(xr1 + sr1);
        const float hh1 = ftanh_(xh1 + (sh1 + bh1) * r1);
        const float hn1 = fmaf(z1, h1_old - hh1, hh1);
        h0_old = hn0; h1_old = hn1;

        if (kh == 0) {
            f16x2 hw; hw.x = (_Float16)hn0; hw.y = (_Float16)hn1;
            *(f16x2*)(&hbuf[rbuf ^ 1][u0]) = hw;
            *(f16x2*)(&hob[(size_t)step * HID + u0]) = hw;
        }
        soft_barrier();   // lgkm-only: xw prefetch stays in flight
    };

    for (int step = 0; step < T; step += 4) {
        STEP(step + 0, 0, zrA, hhA);
        STEP(step + 1, 1, zrB, hhB);
        STEP(step + 2, 0, zrC, hhC);
        STEP(step + 3, 1, zrD, hhD);
    }
}

// ---------------------------------------------------------------------------
// out_proj: out[r,:] = h_f16[r,:] @ wo + bo (fp32 out). Thread = row.
// ---------------------------------------------------------------------------
__global__ __launch_bounds__(256) void out_proj(
    const _Float16* __restrict__ Hf,  // [R,128] f16
    const float* __restrict__ wo,     // [128,5]
    const float* __restrict__ bo,     // [5]
    float*       __restrict__ out,    // [R,5]
    int R)
{
    const int r = blockIdx.x * 256 + threadIdx.x;
    if (r >= R) return;
    const f16x8* xp = (const f16x8*)(Hf + (size_t)r * HID);

    float a0 = bo[0], a1 = bo[1], a2 = bo[2], a3 = bo[3], a4 = bo[4];
#pragma unroll 4
    for (int c = 0; c < 16; ++c) {
        const f16x8 v = xp[c];
#pragma unroll
        for (int e = 0; e < 8; ++e) {
            const float xv = (float)v[e];
            const float* w = wo + (size_t)(8 * c + e) * OUTD;
            a0 = fmaf(xv, w[0], a0);
            a1 = fmaf(xv, w[1], a1);
            a2 = fmaf(xv, w[2], a2);
            a3 = fmaf(xv, w[3], a3);
            a4 = fmaf(xv, w[4], a4);
        }
    }
    float* op = out + (size_t)r * OUTD;
    op[0] = a0; op[1] = a1; op[2] = a2; op[3] = a3; op[4] = a4;
}

// ---------------------------------------------------------------------------
extern "C" void kernel_launch(void* const* d_in, const int* in_sizes, int n_in,
                              void* d_out, int out_size, void* d_ws, size_t ws_size,
                              hipStream_t stream) {
    const float* x   = (const float*)d_in[0];
    const float* k0  = (const float*)d_in[1];
    const float* rk0 = (const float*)d_in[2];
    const float* b0  = (const float*)d_in[3];
    const float* k1  = (const float*)d_in[4];
    const float* rk1 = (const float*)d_in[5];
    const float* b1  = (const float*)d_in[6];
    const float* k2  = (const float*)d_in[7];
    const float* rk2 = (const float*)d_in[8];
    const float* b2  = (const float*)d_in[9];
    const float* wo  = (const float*)d_in[10];
    const float* bo  = (const float*)d_in[11];
    float* out = (float*)d_out;

    const int BT = in_sizes[0] / HID;   // 64*2048 = 131072 rows
    const int T  = T_SEQ;               // 2048
    const int B  = BT / T;              // 64

    // ws layout: [xw f16 BT*384 = 100.6MB][h f16 BT*128 = 33.5MB]
    _Float16* xwbuf = (_Float16*)d_ws;
    _Float16* hbuf  = (_Float16*)((char*)d_ws + (size_t)BT * H3 * sizeof(_Float16));

    const int IPG  = 256;               // in_proj grid (1 WG/CU)
    const int rpw  = BT / IPG;          // 512 rows per WG (exact)
    const int pg   = (BT + 255) / 256;

    in_proj<true>  <<<IPG, 256, 0, stream>>>(x, k0, b0, xwbuf, rpw);
    gru_rec        <<<B, 256, 0, stream>>>(xwbuf, rk0, b0, hbuf, T);

    in_proj<false> <<<IPG, 256, 0, stream>>>(hbuf, k1, b1, xwbuf, rpw);
    gru_rec        <<<B, 256, 0, stream>>>(xwbuf, rk1, b1, hbuf, T);

    in_proj<false> <<<IPG, 256, 0, stream>>>(hbuf, k2, b2, xwbuf, rpw);
    gru_rec        <<<B, 256, 0, stream>>>(xwbuf, rk2, b2, hbuf, T);

    out_proj       <<<pg, 256, 0, stream>>>(hbuf, wo, bo, out, BT);
}

// Round 6
// 1755.806 us; speedup vs baseline: 2.0490x; 2.0490x over previous
//
#include <hip/hip_runtime.h>
#include <hip/hip_bf16.h>
#include <hip/hip_fp16.h>

// ---------------------------------------------------------------------------
// 3-layer GRU (Keras v2, reset_after=True), B=64 T=2048 F=H=128, OUT=5.
// Round 6: LAYER-PIPELINED PERSISTENT KERNEL.
//   Evidence (r4 vs r5): step time ~1100cy for both 2-wave/32-LDS and
//   1-wave/16-LDS configs -> serial-latency-bound, not issue/LDS bound.
//   => run all 3 layers concurrently (192 WGs on 192 CUs), input projection
//   computed INLINE per step (independent work fills latency bubbles).
//   Handoff: global f16 h-planes + per-(layer,batch) flags, agent-scope
//   release/acquire atomics (wbl2/inv across non-coherent XCD L2s).
//   Chunked C=16: 1 publish + 1 poll per 16 steps; staging loads issued at
//   chunk start, LDS-written at ts==7 (vmcnt latency fully hidden).
//   Deadlock-free: producers never wait on consumers (full T buffers).
// ws: 3 h-planes f16 32MB each + flags. No xw buffers, no in_proj kernels.
// ---------------------------------------------------------------------------

#define HID   128
#define H3    384
#define OUTD  5
#define CHK   16            // steps per chunk (publish/poll granularity)

typedef _Float16 f16x2 __attribute__((ext_vector_type(2)));
typedef _Float16 f16x8 __attribute__((ext_vector_type(8)));

__device__ __forceinline__ float fdot2(f16x2 a, f16x2 b, float c) {
#if __has_builtin(__builtin_amdgcn_fdot2)
    return __builtin_amdgcn_fdot2(a, b, c, false);   // v_dot2_f32_f16
#else
    return fmaf((float)a.x, (float)b.x, fmaf((float)a.y, (float)b.y, c));
#endif
}

__device__ __forceinline__ float fexp2(float x) {
#if __has_builtin(__builtin_amdgcn_exp2f)
    return __builtin_amdgcn_exp2f(x);
#else
    return exp2f(x);
#endif
}

__device__ __forceinline__ float frcp(float x) {
#if __has_builtin(__builtin_amdgcn_rcpf)
    return __builtin_amdgcn_rcpf(x);
#else
    return 1.f / x;
#endif
}

// sigmoid(x) = 1/(1+exp(-x)); saturates correctly at +-inf.
__device__ __forceinline__ float fsigmoid(float x) {
    return frcp(1.f + fexp2(x * -1.4426950408889634f));
}

// tanh(x) = 1 - 2/(1+exp(2x)); saturates correctly at +-inf.
__device__ __forceinline__ float ftanh_(float x) {
    return fmaf(-2.f, frcp(1.f + fexp2(x * 2.8853900817779268f)), 1.f);
}

// barrier that does NOT drain vmcnt (unlike __syncthreads): LDS handoff only.
__device__ __forceinline__ void soft_barrier() {
    asm volatile("s_waitcnt lgkmcnt(0)\n\ts_barrier" ::: "memory");
}

// butterfly sum over the kh quad (lanes xor 1, xor 2) on the VALU pipe
__device__ __forceinline__ float quad_sum(float x) {
#if __has_builtin(__builtin_amdgcn_mov_dpp)
    int i1 = __builtin_amdgcn_mov_dpp(__float_as_int(x), 0xB1, 0xF, 0xF, true); // [1,0,3,2]
    x += __int_as_float(i1);
    int i2 = __builtin_amdgcn_mov_dpp(__float_as_int(x), 0x4E, 0xF, 0xF, true); // [2,3,0,1]
    x += __int_as_float(i2);
#else
    x += __shfl_xor(x, 1);
    x += __shfl_xor(x, 2);
#endif
    return x;
}

// ---------------------------------------------------------------------------
__global__ void zero_flags(int* f) {
    if (threadIdx.x < 192) f[threadIdx.x] = 0;
}

// ---------------------------------------------------------------------------
// gru_pipe: 192 WGs = 3 layers x 64 batches, 512 thr (8 waves, 2/SIMD).
// Thread (j = t>>2, kh = t&3): unit j, k-quarter kh. Per step:
//   recurrent dot (48 fdot2, 16-deep) from LDS h double-buffer -> DPP reduce
//   -> gates -> h update -> LDS+global store; inline input projection for
//   step t+1 (48 fdot2 from staged input row, independent -> fills bubbles).
// ---------------------------------------------------------------------------
__global__ __launch_bounds__(512, 2) void gru_pipe(
    const float* __restrict__ x,                         // [64,T,128] fp32
    const float* __restrict__ k0, const float* __restrict__ k1, const float* __restrict__ k2,
    const float* __restrict__ rk0, const float* __restrict__ rk1, const float* __restrict__ rk2,
    const float* __restrict__ b0, const float* __restrict__ b1, const float* __restrict__ b2,
    _Float16* __restrict__ hpl0, _Float16* __restrict__ hpl1, _Float16* __restrict__ hpl2,
    int* flags, int T)
{
    const int blk   = blockIdx.x;
    const int layer = blk >> 6;       // 0..2
    const int b     = blk & 63;       // batch
    const int t     = threadIdx.x;    // 0..511
    const int j     = t >> 2;         // unit 0..127
    const int kh    = t & 3;          // k-quarter
    const int k0i   = kh * 32;
    const int NC    = T / CHK;        // 128 chunks

    const float* Kw = (layer == 0) ? k0  : (layer == 1) ? k1  : k2;
    const float* Rw = (layer == 0) ? rk0 : (layer == 1) ? rk1 : rk2;
    const float* Bs = (layer == 0) ? b0  : (layer == 1) ? b1  : b2;
    const _Float16* hin = (layer == 1) ? hpl0 : hpl1;    // unused for layer 0
    _Float16* hout = (layer == 0) ? hpl0 : (layer == 1) ? hpl1 : hpl2;

    __shared__ __align__(16) _Float16 hb[2][HID];        // own-state dbuf
    __shared__ __align__(16) _Float16 ins[2][CHK][HID];  // staged input rows

    // resident weights: recurrent + input, 3 gates x 16 f16x2 each = 96 VGPRs
    f16x2 wzR[16], wrR[16], whR[16], wzK[16], wrK[16], whK[16];
#pragma unroll
    for (int p = 0; p < 16; ++p) {
        const int k = k0i + 2 * p;
        const float* r0p = Rw + (size_t)k * H3;
        const float* r1p = Rw + (size_t)(k + 1) * H3;
        const float* k0p = Kw + (size_t)k * H3;
        const float* k1p = Kw + (size_t)(k + 1) * H3;
        f16x2 a;
        a.x = (_Float16)r0p[j];       a.y = (_Float16)r1p[j];       wzR[p] = a;
        a.x = (_Float16)r0p[j + 128]; a.y = (_Float16)r1p[j + 128]; wrR[p] = a;
        a.x = (_Float16)r0p[j + 256]; a.y = (_Float16)r1p[j + 256]; whR[p] = a;
        a.x = (_Float16)k0p[j];       a.y = (_Float16)k1p[j];       wzK[p] = a;
        a.x = (_Float16)k0p[j + 128]; a.y = (_Float16)k1p[j + 128]; wrK[p] = a;
        a.x = (_Float16)k0p[j + 256]; a.y = (_Float16)k1p[j + 256]; whK[p] = a;
    }
    const float bzK = Bs[j]       + Bs[384 + j];         // b_in(z)+b_rec(z)
    const float brK = Bs[128 + j] + Bs[384 + 128 + j];   // b_in(r)+b_rec(r)
    const float bhK = Bs[256 + j];                       // b_in(h)
    const float bhR = Bs[384 + 256 + j];                 // b_rec(h) (inside r*)

    int* myflag = flags + layer * 64 + b;
    int* sflag  = flags + (layer - 1) * 64 + b;

    const float*    xb  = x    + (size_t)b * T * HID;
    const _Float16* hib = hin  + (size_t)b * T * HID;
    _Float16*       hob = hout + (size_t)b * T * HID;

    // ---- staging helpers: chunk = CHK rows x 128 f16 = 1024 f16x2 dwords ----
    // thread handles 2 dwords: d = t + 512*i -> row = d>>6, col2 = d&63.
    f16x2 sreg[2];
    auto stage_load = [&](int cc) {
#pragma unroll
        for (int i = 0; i < 2; ++i) {
            const int d  = t + 512 * i;
            const int rw = d >> 6;
            const int c2 = d & 63;
            const size_t off = (size_t)(cc * CHK + rw) * HID + 2 * c2;
            if (layer == 0) {
                const float2 v = *(const float2*)(xb + off);
                f16x2 o; o.x = (_Float16)v.x; o.y = (_Float16)v.y;
                sreg[i] = o;
            } else {
                sreg[i] = *(const f16x2*)(hib + off);
            }
        }
    };
    auto stage_write = [&](int cc) {
        const int slot = cc & 1;
#pragma unroll
        for (int i = 0; i < 2; ++i) {
            const int d  = t + 512 * i;
            const int rw = d >> 6;
            const int c2 = d & 63;
            *(f16x2*)(&ins[slot][rw][2 * c2]) = sreg[i];
        }
    };

    if (t < HID) { hb[0][t] = (_Float16)0.f; hb[1][t] = (_Float16)0.f; }

    // ---- prologue: chunk 0 staged + proj[0] ----
    if (layer > 0 && t == 0) {
        while (__hip_atomic_load(sflag, __ATOMIC_ACQUIRE, __HIP_MEMORY_SCOPE_AGENT) < CHK)
            __builtin_amdgcn_s_sleep(4);
    }
    __syncthreads();
    stage_load(0);
    stage_write(0);      // vmcnt wait here (prologue only)
    __syncthreads();

    float xz, xr, xh;
    {
        const f16x8* ip = (const f16x8*)(&ins[0][0][k0i]);
        float pz = 0.f, pr = 0.f, ph = 0.f;
#pragma unroll
        for (int i = 0; i < 4; ++i) {
            union { f16x8 v; f16x2 p[4]; } u;
            u.v = ip[i];
#pragma unroll
            for (int q = 0; q < 4; ++q) {
                pz = fdot2(u.p[q], wzK[4 * i + q], pz);
                pr = fdot2(u.p[q], wrK[4 * i + q], pr);
                ph = fdot2(u.p[q], whK[4 * i + q], ph);
            }
        }
        xz = quad_sum(pz) + bzK;
        xr = quad_sum(pr) + brK;
        xh = quad_sum(ph) + bhK;
    }

    float h_old = 0.f;

    // ---- main loop over chunks ----
    for (int c = 0; c < NC; ++c) {
        __syncthreads();   // drains vm+lgkm (h stores of prev chunk complete)
        if (t == 0) {
            if (layer < 2 && c > 0)
                __hip_atomic_store(myflag, c * CHK, __ATOMIC_RELEASE, __HIP_MEMORY_SCOPE_AGENT);
            if (layer > 0 && c + 1 < NC) {
                while (__hip_atomic_load(sflag, __ATOMIC_ACQUIRE, __HIP_MEMORY_SCOPE_AGENT) < (c + 2) * CHK)
                    __builtin_amdgcn_s_sleep(4);
            }
        }
        __syncthreads();
        if (c + 1 < NC) stage_load(c + 1);   // loads in flight ~8 steps before ds_write

#pragma unroll 2
        for (int ts = 0; ts < CHK; ++ts) {
            const int tstep = c * CHK + ts;
            const int rbuf  = ts & 1;

            // recurrent dot from own h state
            const f16x8* hp = (const f16x8*)(&hb[rbuf][k0i]);
            float sz = 0.f, sr = 0.f, sh = 0.f;
#pragma unroll
            for (int i = 0; i < 4; ++i) {
                union { f16x8 v; f16x2 p[4]; } u;
                u.v = hp[i];
#pragma unroll
                for (int q = 0; q < 4; ++q) {
                    sz = fdot2(u.p[q], wzR[4 * i + q], sz);
                    sr = fdot2(u.p[q], wrR[4 * i + q], sr);
                    sh = fdot2(u.p[q], whR[4 * i + q], sh);
                }
            }
            sz = quad_sum(sz); sr = quad_sum(sr); sh = quad_sum(sh);

            const float z  = fsigmoid(xz + sz);
            const float r  = fsigmoid(xr + sr);
            const float hh = ftanh_(xh + (sh + bhR) * r);
            const float hn = fmaf(z, h_old - hh, hh);
            h_old = hn;

            if (kh == 0) {
                hb[rbuf ^ 1][j] = (_Float16)hn;
                hob[(size_t)tstep * HID + j] = (_Float16)hn;
            }

            if (ts == 7 && c + 1 < NC) stage_write(c + 1);  // vmcnt hidden (~8 steps old)

            // inline input projection for step t+1 (independent work)
            if (tstep + 1 < T) {
                const int tn = tstep + 1;
                const f16x8* ip = (const f16x8*)(&ins[(tn >> 4) & 1][tn & 15][k0i]);
                float pz = 0.f, pr = 0.f, ph = 0.f;
#pragma unroll
                for (int i = 0; i < 4; ++i) {
                    union { f16x8 v; f16x2 p[4]; } u;
                    u.v = ip[i];
#pragma unroll
                    for (int q = 0; q < 4; ++q) {
                        pz = fdot2(u.p[q], wzK[4 * i + q], pz);
                        pr = fdot2(u.p[q], wrK[4 * i + q], pr);
                        ph = fdot2(u.p[q], whK[4 * i + q], ph);
                    }
                }
                xz = quad_sum(pz) + bzK;
                xr = quad_sum(pr) + brK;
                xh = quad_sum(ph) + bhK;
            }

            soft_barrier();   // lgkm-only: global loads/stores stay in flight
        }
    }

    // final publish
    __syncthreads();
    if (t == 0 && layer < 2)
        __hip_atomic_store(myflag, T, __ATOMIC_RELEASE, __HIP_MEMORY_SCOPE_AGENT);
}

// ---------------------------------------------------------------------------
// out_proj: out[r,:] = h_f16[r,:] @ wo + bo (fp32 out). Thread = row.
// ---------------------------------------------------------------------------
__global__ __launch_bounds__(256) void out_proj(
    const _Float16* __restrict__ Hf,  // [R,128] f16
    const float* __restrict__ wo,     // [128,5]
    const float* __restrict__ bo,     // [5]
    float*       __restrict__ out,    // [R,5]
    int R)
{
    const int r = blockIdx.x * 256 + threadIdx.x;
    if (r >= R) return;
    const f16x8* xp = (const f16x8*)(Hf + (size_t)r * HID);

    float a0 = bo[0], a1 = bo[1], a2 = bo[2], a3 = bo[3], a4 = bo[4];
#pragma unroll 4
    for (int c = 0; c < 16; ++c) {
        const f16x8 v = xp[c];
#pragma unroll
        for (int e = 0; e < 8; ++e) {
            const float xv = (float)v[e];
            const float* w = wo + (size_t)(8 * c + e) * OUTD;
            a0 = fmaf(xv, w[0], a0);
            a1 = fmaf(xv, w[1], a1);
            a2 = fmaf(xv, w[2], a2);
            a3 = fmaf(xv, w[3], a3);
            a4 = fmaf(xv, w[4], a4);
        }
    }
    float* op = out + (size_t)r * OUTD;
    op[0] = a0; op[1] = a1; op[2] = a2; op[3] = a3; op[4] = a4;
}

// ---------------------------------------------------------------------------
extern "C" void kernel_launch(void* const* d_in, const int* in_sizes, int n_in,
                              void* d_out, int out_size, void* d_ws, size_t ws_size,
                              hipStream_t stream) {
    const float* x   = (const float*)d_in[0];
    const float* k0  = (const float*)d_in[1];
    const float* rk0 = (const float*)d_in[2];
    const float* b0  = (const float*)d_in[3];
    const float* k1  = (const float*)d_in[4];
    const float* rk1 = (const float*)d_in[5];
    const float* b1  = (const float*)d_in[6];
    const float* k2  = (const float*)d_in[7];
    const float* rk2 = (const float*)d_in[8];
    const float* b2  = (const float*)d_in[9];
    const float* wo  = (const float*)d_in[10];
    const float* bo  = (const float*)d_in[11];
    float* out = (float*)d_out;

    const int BT = in_sizes[0] / HID;   // 64*2048 = 131072 rows
    const int B  = 64;
    const int T  = BT / B;              // 2048

    // ws layout: 3 f16 h-planes (32MB each) + flags
    const size_t plane = (size_t)BT * HID * sizeof(_Float16);
    _Float16* hpl0 = (_Float16*)d_ws;
    _Float16* hpl1 = (_Float16*)((char*)d_ws + plane);
    _Float16* hpl2 = (_Float16*)((char*)d_ws + 2 * plane);
    int*      flags = (int*)((char*)d_ws + 3 * plane);

    zero_flags<<<1, 256, 0, stream>>>(flags);
    gru_pipe  <<<192, 512, 0, stream>>>(x, k0, k1, k2, rk0, rk1, rk2,
                                        b0, b1, b2, hpl0, hpl1, hpl2, flags, T);
    out_proj  <<<(BT + 255) / 256, 256, 0, stream>>>(hpl2, wo, bo, out, BT);
}